// Round 5
// baseline (1152.736 us; speedup 1.0000x reference)
//
#include <hip/hip_runtime.h>
#include <stdint.h>

#define NROW 8192          // N
#define DDIM 512           // D
#define BB   8             // B
#define PP   4             // P
#define MTOT (BB*NROW)     // 65536 rows

typedef __attribute__((ext_vector_type(8))) short short8;            // 8 bf16 (4 VGPRs)
typedef __attribute__((ext_vector_type(4))) float floatx4;
typedef __attribute__((ext_vector_type(4))) unsigned int uintx4;

// ---- bf16 helpers ----
__device__ inline float bf2f(unsigned short h) { return __uint_as_float(((unsigned)h) << 16); }
__device__ inline unsigned short f2bf_rn(float f) {
    return (unsigned short)((__float_as_uint(f) + 0x8000u) >> 16);   // round-half-up
}
__device__ inline unsigned pack_bf16(float a, float b) {
    unsigned ua = __float_as_uint(a) + 0x8000u;
    unsigned ub = __float_as_uint(b) + 0x8000u;
    return __builtin_amdgcn_perm(ub, ua, 0x07060302u);
}
__device__ inline uintx4 packA(const floatx4& v0, const floatx4& v1) {
    uintx4 w = { pack_bf16(v0[0], v0[1]), pack_bf16(v0[2], v0[3]),
                 pack_bf16(v1[0], v1[1]), pack_bf16(v1[2], v1[3]) };
    return w;
}

template <typename T> __device__ inline float loadF(const T* p);
template <> __device__ inline float loadF<float>(const float* p) { return *p; }
template <> __device__ inline float loadF<unsigned short>(const unsigned short* p) { return bf2f(*p); }

// ---- histogram: cnt[i][r] = multiplicity of r in groups[i] ----
__global__ void hist_kernel(const int* __restrict__ groups, float* __restrict__ cnt) {
    int t = blockIdx.x * 256 + threadIdx.x;     // 0..32767
    int i = t >> 13;
    atomicAdd(&cnt[i * NROW + groups[t]], 1.0f);
}

// ---- W -> bf16, pre-swizzled into MFMA B-fragment order ----
// Wsw[i][kb 0..15][gtile 0..31][lane 0..63][e 0..7] = bf16(W[i][k][n])
//   n = gtile*16 + (lane&15), k = kb*32 + (lane>>4)*8 + e
__global__ void transpose_w(const float* __restrict__ W, unsigned short* __restrict__ Wsw) {
    int u = blockIdx.x * 256 + threadIdx.x;     // 0..131071 (one 16B chunk each)
    int i    = u >> 15;
    int kb   = (u >> 11) & 15;
    int gt   = (u >> 6) & 31;
    int lane = u & 63;
    int n  = gt * 16 + (lane & 15);
    int k0 = kb * 32 + (lane >> 4) * 8;
    const float* wp = W + i * 262144 + k0 * 512 + n;
    unsigned hp[4];
    #pragma unroll
    for (int j = 0; j < 4; ++j)
        hp[j] = pack_bf16(wp[(2*j) * 512], wp[(2*j+1) * 512]);
    uintx4 w = {hp[0], hp[1], hp[2], hp[3]};
    *(uintx4*)(Wsw + (size_t)u * 8) = w;
}

// ---- x (fp32) -> bf16, same rounding as pack path ----
__global__ void cvt_bf16(const float* __restrict__ x, unsigned short* __restrict__ xb) {
    size_t t = (size_t)blockIdx.x * 256 + threadIdx.x;   // 8 elems each
    const floatx4* p = (const floatx4*)x + t * 2;
    floatx4 v0 = p[0], v1 = p[1];
    *(uintx4*)(xb + t * 8) = packA(v0, v1);
}

// ---- fused round GEMM: barrier-free per-wave dataflow ----
// Block: 64x64 output tile; wave w accumulates UNSCALED srcA@W_w over K=512
// (i == wave). No LDS, no barriers in the main loop: each lane loads its A
// fragment straight from row-major bf16 global (per-16-lane-group reads
// cover full 64B lines -> no over-fetch) and its B fragment from the
// L2-resident pre-swizzled Wsw. A ring-2 issued 2 kb ahead, B ring-2 issued
// 1 kb ahead; compiler inserts counted vmcnts (no barrier to defeat them).
// Per-row scale c_w[m] applied once to the f32 acc; waves combined through
// a small LDS buffer in the epilogue only:
//   dst = add + scale * sum_w c_w[m] * (srcA @ W_w)[m,n]
template <typename AddT, bool WF32, bool WBF16>
__global__ __launch_bounds__(256, 3)
void gemm_round(const unsigned short* __restrict__ srcA, const AddT* __restrict__ srcAdd,
                const unsigned short* __restrict__ Wsw, const float* __restrict__ cnt,
                float* __restrict__ dstF, unsigned short* __restrict__ dstB, float scale)
{
    __shared__ __align__(16) float sE[4 * 1104];   // [wave][16 rows][69] epilogue only

    const int t    = threadIdx.x;
    const int wave = t >> 6;                 // wave == i
    const int lane = t & 63;
    const int nb   = blockIdx.x;             // 0..7, fastest-varying
    const int m0   = blockIdx.y * 64;

    // A fragment bases: lane l covers row a*16+(l&15), k-chunk (l>>4)*8.
    // Per-kb advance = 32 elems = 64B -> folds into the 13-bit imm offset.
    const unsigned short* apA[4];
    #pragma unroll
    for (int a = 0; a < 4; ++a)
        apA[a] = srcA + (size_t)(m0 + a * 16 + (lane & 15)) * DDIM + ((lane >> 4) << 3);

    // B fragment base: Wsw[((wave*16+kb)*32 + nb*4 + b)*512 + lane*8]
    const unsigned short* bp = Wsw + ((size_t)(wave * 16) * 32 + nb * 4) * 512 + lane * 8;

    floatx4 acc[4][4] = {};
    short8 Ar[2][4], Br[2][4];

    // prologue: A for kb=0,1 (depth 2), B for kb=0 (depth 1)
    #pragma unroll
    for (int a = 0; a < 4; ++a) Ar[0][a] = *(const short8*)(apA[a]);
    #pragma unroll
    for (int a = 0; a < 4; ++a) Ar[1][a] = *(const short8*)(apA[a] + 32);
    #pragma unroll
    for (int b = 0; b < 4; ++b) Br[0][b] = *(const short8*)(bp + b * 512);

    #pragma unroll
    for (int kb = 0; kb < 16; ++kb) {
        // B for kb+1 (in flight across this kb's MFMAs)
        if (kb < 15) {
            #pragma unroll
            for (int b = 0; b < 4; ++b)
                Br[(kb + 1) & 1][b] = *(const short8*)(bp + (size_t)(kb + 1) * 16384 + b * 512);
        }

        __builtin_amdgcn_s_setprio(1);
        #pragma unroll
        for (int a = 0; a < 4; ++a)
            #pragma unroll
            for (int b = 0; b < 4; ++b)
                acc[a][b] = __builtin_amdgcn_mfma_f32_16x16x32_bf16(Ar[kb & 1][a], Br[kb & 1][b], acc[a][b], 0, 0, 0);
        __builtin_amdgcn_s_setprio(0);

        // A for kb+2 into the slot just consumed (ring-2, depth-2)
        if (kb < 14) {
            #pragma unroll
            for (int a = 0; a < 4; ++a)
                Ar[kb & 1][a] = *(const short8*)(apA[a] + (kb + 2) * 32);
        }
    }

    // ---- epilogue ----
    // hoist add-source loads (latency overlaps the LDS combine) + count scales
    float addv[4][4], cs[4][4];
    #pragma unroll
    for (int a = 0; a < 4; ++a)
        #pragma unroll
        for (int e = 0; e < 4; ++e)
            addv[a][e] = loadF(srcAdd + (size_t)(m0 + a * 16 + wave * 4 + e) * DDIM
                                      + (size_t)nb * 64 + lane);
    #pragma unroll
    for (int a = 0; a < 4; ++a)
        #pragma unroll
        for (int q = 0; q < 4; ++q)
            cs[a][q] = cnt[wave * NROW + ((m0 + a * 16 + (lane >> 4) * 4 + q) & (NROW - 1))];

    // combine 4 waves through LDS, 16-row chunks (stride 69 = conflict-free)
    #pragma unroll
    for (int a = 0; a < 4; ++a) {
        float* se = sE + wave * 1104;
        #pragma unroll
        for (int b = 0; b < 4; ++b)
            #pragma unroll
            for (int q = 0; q < 4; ++q)
                se[((lane >> 4) * 4 + q) * 69 + b * 16 + (lane & 15)] = acc[a][b][q] * cs[a][q];
        __syncthreads();
        #pragma unroll
        for (int e = 0; e < 4; ++e) {
            const int r = wave * 4 + e;
            const size_t m = (size_t)(m0 + a * 16 + r);
            const size_t n = (size_t)nb * 64 + lane;
            const float sum = sE[0 * 1104 + r * 69 + lane] + sE[1 * 1104 + r * 69 + lane]
                            + sE[2 * 1104 + r * 69 + lane] + sE[3 * 1104 + r * 69 + lane];
            const float f = addv[a][e] + scale * sum;
            if constexpr (WF32)  dstF[m * DDIM + n] = f;
            if constexpr (WBF16) dstB[m * DDIM + n] = f2bf_rn(f);
        }
        if (a < 3) __syncthreads();
    }
}

extern "C" void kernel_launch(void* const* d_in, const int* in_sizes, int n_in,
                              void* d_out, int out_size, void* d_ws, size_t ws_size,
                              hipStream_t stream) {
    const float* x      = (const float*)d_in[0];   // (8, 8192, 512) fp32
    const float* W      = (const float*)d_in[1];   // (4, 512, 512) fp32
    const int*   groups = (const int*)d_in[2];     // (4, 512, 16) int32
    float* out = (float*)d_out;                    // (8, 8192, 512) fp32

    char* ws = (char*)d_ws;
    float*          cnt = (float*)ws;                               // 128 KB
    unsigned short* Wsw = (unsigned short*)(ws + 131072);           // 2 MB
    unsigned short* U1  = (unsigned short*)(ws + 131072 + 2097152); // 64 MB bf16
    unsigned short* U2  = U1 + (size_t)MTOT * DDIM;                 // 64 MB bf16 (aliases xb)

    hipMemsetAsync(cnt, 0, PP * NROW * sizeof(float), stream);
    hist_kernel<<<32768 / 256, 256, 0, stream>>>(groups, cnt);
    transpose_w<<<131072 / 256, 256, 0, stream>>>(W, Wsw);
    cvt_bf16<<<(MTOT * DDIM / 8) / 256, 256, 0, stream>>>(x, U2);   // xb = U2 slot

    // nb fastest-varying: with grid.x=8, XCD = linear_id % 8 = nb, so each
    // XCD's L2 holds exactly one 256KB nb-slice of Wsw (perfect B pinning);
    // the 8 blocks sharing an A-tile dispatch together (A via L3).
    dim3 grid(DDIM / 64, MTOT / 64);               // (8, 1024)
    // round 1: A=bf16(x), add=x (fp32) -> out (fp32) + U1 (bf16)
    gemm_round<float, true, true><<<grid, 256, 0, stream>>>(U2, x, Wsw, cnt, out, U1, 1.0f);
    // round 2: A=U1, add=out (fp32) -> U2 (bf16; xb is dead)
    gemm_round<float, false, true><<<grid, 256, 0, stream>>>(U1, out, Wsw, cnt, nullptr, U2, 0.5f);
    // round 3: A=U2, add=U2 (bf16) -> out (fp32)
    gemm_round<unsigned short, true, false><<<grid, 256, 0, stream>>>(U2, U2, Wsw, cnt, out, nullptr, 1.0f / 3.0f);
}

// Round 6
// 1003.807 us; speedup vs baseline: 1.1484x; 1.1484x over previous
//
#include <hip/hip_runtime.h>
#include <stdint.h>

#define NROW 8192          // N
#define DDIM 512           // D
#define BB   8             // B
#define PP   4             // P
#define MTOT (BB*NROW)     // 65536 rows

typedef __attribute__((ext_vector_type(8))) short short8;            // 8 bf16 (4 VGPRs)
typedef __attribute__((ext_vector_type(4))) float floatx4;
typedef __attribute__((ext_vector_type(4))) unsigned int uintx4;

// ---- bf16 helpers ----
__device__ inline float bf2f(unsigned short h) { return __uint_as_float(((unsigned)h) << 16); }
__device__ inline unsigned short f2bf_rn(float f) {
    return (unsigned short)((__float_as_uint(f) + 0x8000u) >> 16);   // round-half-up
}
__device__ inline unsigned pack_bf16(float a, float b) {
    unsigned ua = __float_as_uint(a) + 0x8000u;
    unsigned ub = __float_as_uint(b) + 0x8000u;
    return __builtin_amdgcn_perm(ub, ua, 0x07060302u);
}
__device__ inline uintx4 packA(const floatx4& v0, const floatx4& v1) {
    uintx4 w = { pack_bf16(v0[0], v0[1]), pack_bf16(v0[2], v0[3]),
                 pack_bf16(v1[0], v1[1]), pack_bf16(v1[2], v1[3]) };
    return w;
}

template <typename T> __device__ inline float loadF(const T* p);
template <> __device__ inline float loadF<float>(const float* p) { return *p; }
template <> __device__ inline float loadF<unsigned short>(const unsigned short* p) { return bf2f(*p); }

// async global->LDS, 16B per lane; LDS dest = wave-uniform base + lane*16
__device__ inline void glds16(const void* g, void* l) {
    __builtin_amdgcn_global_load_lds(
        (const __attribute__((address_space(1))) void*)g,
        (__attribute__((address_space(3))) void*)l, 16, 0, 0);
}

// counted-vmcnt barrier: drain LDS ops + all but N outstanding VMEM ops,
// then s_barrier. Keeps the 2-ahead glds prefetch in flight (T4).
#define SYNC_VM(N) do {                                                 \
    __builtin_amdgcn_sched_barrier(0);                                  \
    asm volatile("s_waitcnt vmcnt(" #N ") lgkmcnt(0)" ::: "memory");    \
    __builtin_amdgcn_s_barrier();                                       \
    __builtin_amdgcn_sched_barrier(0);                                  \
} while (0)

// ---- histogram: cnt[i][r] = multiplicity of r in groups[i] ----
__global__ void hist_kernel(const int* __restrict__ groups, float* __restrict__ cnt) {
    int t = blockIdx.x * 256 + threadIdx.x;     // 0..32767
    int i = t >> 13;
    atomicAdd(&cnt[i * NROW + groups[t]], 1.0f);
}

// ---- W -> bf16, pre-swizzled into MFMA B-fragment order ----
// Wsw[i][kb 0..15][gtile 0..31][lane 0..63][e 0..7] = bf16(W[i][k][n])
//   n = gtile*16 + (lane&15), k = kb*32 + (lane>>4)*8 + e
__global__ void transpose_w(const float* __restrict__ W, unsigned short* __restrict__ Wsw) {
    int u = blockIdx.x * 256 + threadIdx.x;     // 0..131071 (one 16B chunk each)
    int i    = u >> 15;
    int kb   = (u >> 11) & 15;
    int gt   = (u >> 6) & 31;
    int lane = u & 63;
    int n  = gt * 16 + (lane & 15);
    int k0 = kb * 32 + (lane >> 4) * 8;
    const float* wp = W + i * 262144 + k0 * 512 + n;
    unsigned hp[4];
    #pragma unroll
    for (int j = 0; j < 4; ++j)
        hp[j] = pack_bf16(wp[(2*j) * 512], wp[(2*j+1) * 512]);
    uintx4 w = {hp[0], hp[1], hp[2], hp[3]};
    *(uintx4*)(Wsw + (size_t)u * 8) = w;
}

// ---- x (fp32) -> bf16, same rounding as pack path ----
__global__ void cvt_bf16(const float* __restrict__ x, unsigned short* __restrict__ xb) {
    size_t t = (size_t)blockIdx.x * 256 + threadIdx.x;   // 8 elems each
    const floatx4* p = (const floatx4*)x + t * 2;
    floatx4 v0 = p[0], v1 = p[1];
    *(uintx4*)(xb + t * 8) = packA(v0, v1);
}

// ---- fused round GEMM: A-resident-in-LDS, i-serial, B-shared ----
// Block: 128x128 output tile, 4 waves in 2x2, wave tile 64x64.
// A (128 rows x K=512 bf16 = 128KB) persists in LDS for the block lifetime,
// staged via global_load_lds progressively during the i=0 pass (2 glds/thread
// per step, hidden under MFMA). B (8KB per (i,kb)) staged into a 3-buffer
// ring, 2 steps ahead, shared by all 4 waves. i runs SERIALLY so B is loaded
// once per block per (i,kb); per-row scale c_i[m] is applied in registers at
// each i boundary:  tot += c_i[row] * T_i;  waves own disjoint quadrants ->
// no cross-wave epilogue.  dst = add + scale * tot.
// One counted-vmcnt barrier per step; glds prefetch never drained early.
template <typename AddT, bool WF32, bool WBF16>
__global__ __launch_bounds__(256, 1)
void gemm_round(const unsigned short* __restrict__ srcA, const AddT* __restrict__ srcAdd,
                const unsigned short* __restrict__ Wsw, const float* __restrict__ cnt,
                float* __restrict__ dstF, unsigned short* __restrict__ dstB, float scale)
{
    __shared__ __align__(16) unsigned short sA[128 * 512];   // 128KB [kb16][fa8][lane][8]
    __shared__ __align__(16) unsigned short sB[3][8 * 512];  // 24KB  [buf][fb8][lane][8]

    const int t    = threadIdx.x;
    const int wave = t >> 6;
    const int lane = t & 63;
    const int wr   = wave >> 1;              // wave row (0..1)
    const int wc   = wave & 1;               // wave col (0..1)
    const int nb   = blockIdx.x;             // 0..3 (128 cols each)
    const int m0   = blockIdx.y * 128;

    // staging sources: thread handles frag f = wave*2+j (A: row group; B: gtile)
    const unsigned short* aSrc[2];
    const unsigned short* bSrc[2];
    #pragma unroll
    for (int j = 0; j < 2; ++j) {
        aSrc[j] = srcA + (size_t)(m0 + (wave * 2 + j) * 16 + (lane & 15)) * DDIM
                       + ((lane >> 4) << 3);
        bSrc[j] = Wsw + (size_t)(nb * 8 + wave * 2 + j) * 512 + lane * 8;
    }

    floatx4 Ti[4][4];
    floatx4 tot[4][4] = {};
    float cs[4][4];

    // stage A[kb] (8KB: frags fa=0..7, this thread does fa=wave*2+j)
    auto stageA = [&](int kb) {
        #pragma unroll
        for (int j = 0; j < 2; ++j)
            glds16(aSrc[j] + kb * 32, &sA[(kb * 8 + wave * 2 + j) * 512]);
    };
    // stage B[step s] (8KB) into buffer s%3
    auto stageB = [&](int s) {
        #pragma unroll
        for (int j = 0; j < 2; ++j)
            glds16(bSrc[j] + (size_t)s * 16384, &sB[s % 3][(wave * 2 + j) * 512]);
    };

    // ---- prologue: A(0),A(1), B(0),B(1) in flight
    stageA(0); stageA(1); stageB(0); stageB(1);

    #pragma unroll
    for (int s = 0; s < 64; ++s) {
        const int i = s >> 4, kb = s & 15;

        // barrier: drain glds for step s (staged at s-2), keep the newer 4/2
        if (s <= 14) SYNC_VM(4); else SYNC_VM(2);

        // fragments from LDS (conflict-free: base + lane*16B)
        short8 af[4], bf[4];
        #pragma unroll
        for (int a = 0; a < 4; ++a)
            af[a] = *(const short8*)(&sA[(kb * 8 + wr * 4 + a) * 512] + lane * 8);
        #pragma unroll
        for (int b = 0; b < 4; ++b)
            bf[b] = *(const short8*)(&sB[s % 3][(wc * 4 + b) * 512] + lane * 8);

        // count-scale prefetch for this i (before staging glds: keeps the
        // vmcnt bookkeeping conservative-safe)
        if (kb == 14) {
            #pragma unroll
            for (int a = 0; a < 4; ++a)
                #pragma unroll
                for (int q = 0; q < 4; ++q)
                    cs[a][q] = cnt[i * NROW +
                        ((m0 + wr * 64 + a * 16 + (lane >> 4) * 4 + q) & (NROW - 1))];
        }

        // prefetch staging, 2 steps ahead
        if (s < 62)  stageB(s + 2);
        if (s <= 13) stageA(s + 2);          // A fully staged by end of i=0 pass

        // 16 MFMA (64x64 wave tile, K=32)
        #pragma unroll
        for (int a = 0; a < 4; ++a)
            #pragma unroll
            for (int b = 0; b < 4; ++b)
                Ti[a][b] = __builtin_amdgcn_mfma_f32_16x16x32_bf16(
                    af[a], bf[b],
                    kb == 0 ? (floatx4){0.f, 0.f, 0.f, 0.f} : Ti[a][b], 0, 0, 0);

        // i boundary: fold scaled T_i into the running total (register-local)
        if (kb == 15) {
            #pragma unroll
            for (int a = 0; a < 4; ++a)
                #pragma unroll
                for (int b = 0; b < 4; ++b)
                    #pragma unroll
                    for (int q = 0; q < 4; ++q)
                        tot[a][b][q] += cs[a][q] * Ti[a][b][q];
        }
    }

    // ---- epilogue: dst = add + scale*tot (wave-private quadrant) ----
    const size_t n0 = (size_t)nb * 128 + wc * 64;
    #pragma unroll
    for (int a = 0; a < 4; ++a) {
        #pragma unroll
        for (int q = 0; q < 4; ++q) {
            const size_t m = (size_t)(m0 + wr * 64 + a * 16 + (lane >> 4) * 4 + q);
            #pragma unroll
            for (int b = 0; b < 4; ++b) {
                const size_t idx = m * DDIM + n0 + b * 16 + (lane & 15);
                const float f = loadF(srcAdd + idx) + scale * tot[a][b][q];
                if constexpr (WF32)  dstF[idx] = f;
                if constexpr (WBF16) dstB[idx] = f2bf_rn(f);
            }
        }
    }
}

extern "C" void kernel_launch(void* const* d_in, const int* in_sizes, int n_in,
                              void* d_out, int out_size, void* d_ws, size_t ws_size,
                              hipStream_t stream) {
    const float* x      = (const float*)d_in[0];   // (8, 8192, 512) fp32
    const float* W      = (const float*)d_in[1];   // (4, 512, 512) fp32
    const int*   groups = (const int*)d_in[2];     // (4, 512, 16) int32
    float* out = (float*)d_out;                    // (8, 8192, 512) fp32

    char* ws = (char*)d_ws;
    float*          cnt = (float*)ws;                               // 128 KB
    unsigned short* Wsw = (unsigned short*)(ws + 131072);           // 2 MB
    unsigned short* U1  = (unsigned short*)(ws + 131072 + 2097152); // 64 MB bf16
    unsigned short* U2  = U1 + (size_t)MTOT * DDIM;                 // 64 MB bf16 (aliases xb)

    hipMemsetAsync(cnt, 0, PP * NROW * sizeof(float), stream);
    hist_kernel<<<32768 / 256, 256, 0, stream>>>(groups, cnt);
    transpose_w<<<131072 / 256, 256, 0, stream>>>(W, Wsw);
    cvt_bf16<<<(MTOT * DDIM / 8) / 256, 256, 0, stream>>>(x, U2);   // xb = U2 slot

    // nb fastest: the 4 blocks sharing an A-tile dispatch together (A via L3);
    // Wsw (2MB) is L2-resident on every XCD.
    dim3 grid(DDIM / 128, MTOT / 128);             // (4, 512)
    // round 1: A=bf16(x), add=x (fp32) -> out (fp32) + U1 (bf16)
    gemm_round<float, true, true><<<grid, 256, 0, stream>>>(U2, x, Wsw, cnt, out, U1, 1.0f);
    // round 2: A=U1, add=out (fp32) -> U2 (bf16; xb is dead)
    gemm_round<float, false, true><<<grid, 256, 0, stream>>>(U1, out, Wsw, cnt, nullptr, U2, 0.5f);
    // round 3: A=U2, add=U2 (bf16) -> out (fp32)
    gemm_round<unsigned short, true, false><<<grid, 256, 0, stream>>>(U2, U2, Wsw, cnt, out, nullptr, 1.0f / 3.0f);
}